// Round 9
// baseline (923.501 us; speedup 1.0000x reference)
//
#include <hip/hip_runtime.h>
#include <math.h>
#include <stdint.h>

#define Bn 2
#define Ln 2048
#define Dn 1024
#define Hn 16
#define DHn 64
#define Un 1228
#define BHn (Bn*Hn)
#define WIN 64                       // exact-refine window: ranks [U-32, U+32)
#define SCALE 0.125f
// pre-split power-of-2 scales (dodge fp16 subnormal flush on lo terms)
#define SXf 16.0f     // x
#define SWf 256.0f    // all W
#define SQf 16.0f     // Q, K
#define SVf 16.0f     // V
#define SPf 16.0f     // softmax P
#define ESC_PROJ (1.0f / 4096.0f)    // 1/(SX*SW)
#define ESC_OUT  (1.0f / 65536.0f)   // 1/(SPf*SVf*SWf)
#define PSC (SCALE / 256.0f)         // score unscale: 1/(SQ*SQ) * SCALE

typedef _Float16 f16;
typedef __attribute__((ext_vector_type(8))) _Float16 f16x8;
typedef __attribute__((ext_vector_type(4))) float f32x4;
struct h4s { f16 x, y, z, w; };

__device__ __forceinline__ void splitf16(float f, f16& hi, f16& lo) {
  hi = (f16)f;                 // RTNE
  lo = (f16)(f - (float)hi);   // residual, ~22 mantissa bits total
}

// async global->LDS, 16B per lane (wave-uniform base + lane*16)
__device__ __forceinline__ void gl_lds16(const void* g, void* l) {
  __builtin_amdgcn_global_load_lds(
      (const __attribute__((address_space(1))) void*)g,
      (__attribute__((address_space(3))) void*)l, 16, 0, 0);
}

#define MFMA(a, b, c) __builtin_amdgcn_mfma_f32_16x16x32_f16((a), (b), (c), 0, 0, 0)

// ---------------- split x*16 -> xh, xl ----------------
__global__ __launch_bounds__(256) void split_kernel(
    const float* __restrict__ in, f16* __restrict__ oh, f16* __restrict__ ol, int n4) {
  int i = blockIdx.x * 256 + threadIdx.x;
  if (i >= n4) return;
  float4 v = ((const float4*)in)[i];
  h4s h, l;
  splitf16(v.x * SXf, h.x, l.x); splitf16(v.y * SXf, h.y, l.y);
  splitf16(v.z * SXf, h.z, l.z); splitf16(v.w * SXf, h.w, l.w);
  ((h4s*)oh)[i] = h; ((h4s*)ol)[i] = l;
}

// ------- transpose + split W*256 for all 4 weights: Wt[z*1024 + n][k]; lo only for Wk -------
__global__ __launch_bounds__(256) void tsplit_w4(
    const float* __restrict__ W0, const float* __restrict__ W1,
    const float* __restrict__ W2, const float* __restrict__ W3,
    f16* __restrict__ oh, f16* __restrict__ ol) {
  __shared__ float ts[64][65];
  const int t = threadIdx.x;
  const int r0 = blockIdx.x * 64, c0 = blockIdx.y * 64;
  const int z = blockIdx.z;
  const float* in = (z == 0) ? W0 : (z == 1) ? W1 : (z == 2) ? W2 : W3;
#pragma unroll
  for (int c = 0; c < 4; ++c) {
    int f = (c * 256 + t) * 4; int row = f >> 6, col = f & 63;
    float4 v = *(const float4*)&in[(size_t)(r0 + row) * Dn + c0 + col];
    ts[row][col] = v.x; ts[row][col + 1] = v.y; ts[row][col + 2] = v.z; ts[row][col + 3] = v.w;
  }
  __syncthreads();
#pragma unroll
  for (int c = 0; c < 4; ++c) {
    int f = (c * 256 + t) * 4; int crow = f >> 6, rcol = f & 63;
    h4s h, l;
    splitf16(ts[rcol + 0][crow] * SWf, h.x, l.x);
    splitf16(ts[rcol + 1][crow] * SWf, h.y, l.y);
    splitf16(ts[rcol + 2][crow] * SWf, h.z, l.z);
    splitf16(ts[rcol + 3][crow] * SWf, h.w, l.w);
    size_t o = (size_t)(z * 1024 + c0 + crow) * Dn + r0 + rcol;
    *(h4s*)&oh[o] = h;
    if (z == 1) *(h4s*)&ol[o] = l;     // lo needed only for Wk (3-MFMA K segment)
  }
}

// ------- fused QKV GEMM, per-segment precision: Q 1-MFMA, K 3-MFMA, V 1-MFMA -------
// grid (24, 32): bx 0-7 Q, 8-15 K, 16-23 V (segment block-uniform).
__global__ void gemm_qkv(
    const f16* __restrict__ Ah, const f16* __restrict__ Al,
    const f16* __restrict__ Bth, const f16* __restrict__ Btl,
    const float* __restrict__ bq, const float* __restrict__ bk, const float* __restrict__ bv,
    f16* __restrict__ Qbh,
    float* __restrict__ Kf, f16* __restrict__ Kbh,
    f16* __restrict__ Vh16, int K) {
  __shared__ f16 sAh[128 * 32], sAl[128 * 32], sBh[128 * 32], sBl[128 * 32];
  const int t = threadIdx.x;
  const int w = t >> 6, lane = t & 63, lm = lane & 15, q = lane >> 4;
  const int wr = w >> 1, wc = w & 1;
  const int n0 = blockIdx.x * 128, m0 = blockIdx.y * 128;
  const int seg = blockIdx.x >> 3;
  f32x4 acc[4][4] = {};
  for (int k0 = 0; k0 < K; k0 += 32) {
    const f16* s0 = Ah + (size_t)m0 * K + k0;
    const f16* s1 = Al + (size_t)m0 * K + k0;
    const f16* s2 = Bth + (size_t)n0 * K + k0;
    const f16* s3 = Btl + (size_t)n0 * K + k0;
#pragma unroll
    for (int c = 0; c < 2; ++c) {
      int f = (c * 256 + t) * 8; int row = f >> 5, col = f & 31;
      size_t go = (size_t)row * K + col;
      gl_lds16(s0 + go, &sAh[f]);
      gl_lds16(s2 + go, &sBh[f]);
      if (seg == 1) {
        gl_lds16(s1 + go, &sAl[f]);
        gl_lds16(s3 + go, &sBl[f]);
      }
    }
    __syncthreads();
    f16x8 a_h[4], a_l[4], b_h[4], b_l[4];
#pragma unroll
    for (int mi = 0; mi < 4; ++mi) {
      int r = (wr * 64 + mi * 16 + lm) * 32 + q * 8;
      a_h[mi] = *(const f16x8*)&sAh[r];
      if (seg == 1) a_l[mi] = *(const f16x8*)&sAl[r];
    }
#pragma unroll
    for (int ni = 0; ni < 4; ++ni) {
      int r = (wc * 64 + ni * 16 + lm) * 32 + q * 8;
      b_h[ni] = *(const f16x8*)&sBh[r];
      if (seg == 1) b_l[ni] = *(const f16x8*)&sBl[r];
    }
    if (seg == 1) {
#pragma unroll
      for (int mi = 0; mi < 4; ++mi)
#pragma unroll
        for (int ni = 0; ni < 4; ++ni) {
          acc[mi][ni] = MFMA(a_h[mi], b_h[ni], acc[mi][ni]);
          acc[mi][ni] = MFMA(a_h[mi], b_l[ni], acc[mi][ni]);
          acc[mi][ni] = MFMA(a_l[mi], b_h[ni], acc[mi][ni]);
        }
    } else {
#pragma unroll
      for (int mi = 0; mi < 4; ++mi)
#pragma unroll
        for (int ni = 0; ni < 4; ++ni)
          acc[mi][ni] = MFMA(a_h[mi], b_h[ni], acc[mi][ni]);
    }
    __syncthreads();
  }
#pragma unroll
  for (int mi = 0; mi < 4; ++mi)
#pragma unroll
    for (int ni = 0; ni < 4; ++ni) {
      int nglob = n0 + wc * 64 + ni * 16;
      int c = (nglob & 1023) + lm;
      const float* bp = (seg == 0) ? bq : (seg == 1) ? bk : bv;
      float bvv = bp[c];
#pragma unroll
      for (int r = 0; r < 4; ++r) {
        int grow = m0 + wr * 64 + mi * 16 + q * 4 + r;
        float v = acc[mi][ni][r] * ESC_PROJ + bvv;
        size_t o = (size_t)grow * 1024 + c;
        if (seg == 0) {
          Qbh[o] = (f16)(v * SQf);
        } else if (seg == 1) {
          Kf[o] = v;
          Kbh[o] = (f16)(v * SQf);
        } else {
          Vh16[o] = (f16)(v * SVf);
        }
      }
    }
}

// ---------------- transpose V (f16): Vh16[b,l,D] -> Vt[bh*64+d][L] ----------------
__global__ __launch_bounds__(256) void tsplit_v(
    const f16* __restrict__ Vh16, f16* __restrict__ out) {
  __shared__ f16 ts[64][72];
  const int t = threadIdx.x;
  const int l0 = blockIdx.x * 64;
  const int bh = blockIdx.y, b = bh >> 4, h = bh & 15;
#pragma unroll
  for (int c = 0; c < 2; ++c) {
    int e = c * 256 + t; int row = e >> 3, cg = e & 7;
    *(uint4*)&ts[row][cg * 8] =
        *(const uint4*)&Vh16[((size_t)b * Ln + l0 + row) * Dn + h * DHn + cg * 8];
  }
  __syncthreads();
#pragma unroll
  for (int c = 0; c < 2; ++c) {
    int e = c * 256 + t; int drow = e >> 3, lg = e & 7;
    f16 tmp[8];
#pragma unroll
    for (int j = 0; j < 8; ++j) tmp[j] = ts[lg * 8 + j][drow];
    *(uint4*)&out[((size_t)bh * DHn + drow) * Ln + l0 + lg * 8] = *(uint4*)tmp;
  }
}

// ---------------- out-proj GEMM, 1-MFMA (A f16, B f16): 128x64 tiles ----------------
__global__ __launch_bounds__(256, 4) void gemm_a1(
    const f16* __restrict__ A, const f16* __restrict__ Bth,
    const float* __restrict__ bias, float escale,
    float* __restrict__ Cf, int M, int N, int K) {
  __shared__ f16 sA[128 * 32], sB[64 * 32];
  const int t = threadIdx.x;
  const int w = t >> 6, lane = t & 63, lm = lane & 15, q = lane >> 4;
  const int wr = w >> 1, wc = w & 1;
  const int n0 = blockIdx.x * 64, m0 = blockIdx.y * 128;
  f32x4 acc[4][2] = {};
  for (int k0 = 0; k0 < K; k0 += 32) {
    const f16* s0 = A + (size_t)m0 * K + k0;
    const f16* s2 = Bth + (size_t)n0 * K + k0;
#pragma unroll
    for (int c = 0; c < 2; ++c) {
      int f = (c * 256 + t) * 8; int row = f >> 5, col = f & 31;
      gl_lds16(s0 + (size_t)row * K + col, &sA[f]);
    }
    {
      int f = t * 8; int row = f >> 5, col = f & 31;
      gl_lds16(s2 + (size_t)row * K + col, &sB[f]);
    }
    __syncthreads();
    f16x8 a_[4], b_[2];
#pragma unroll
    for (int mi = 0; mi < 4; ++mi)
      a_[mi] = *(const f16x8*)&sA[(wr * 64 + mi * 16 + lm) * 32 + q * 8];
#pragma unroll
    for (int ni = 0; ni < 2; ++ni)
      b_[ni] = *(const f16x8*)&sB[(wc * 32 + ni * 16 + lm) * 32 + q * 8];
#pragma unroll
    for (int mi = 0; mi < 4; ++mi)
#pragma unroll
      for (int ni = 0; ni < 2; ++ni)
        acc[mi][ni] = MFMA(a_[mi], b_[ni], acc[mi][ni]);
    __syncthreads();
  }
#pragma unroll
  for (int mi = 0; mi < 4; ++mi)
#pragma unroll
    for (int ni = 0; ni < 2; ++ni) {
      int gcol = n0 + wc * 32 + ni * 16 + lm;
      float bvv = bias[gcol];
#pragma unroll
      for (int r = 0; r < 4; ++r) {
        int grow = m0 + wr * 64 + mi * 16 + q * 4 + r;
        Cf[(size_t)grow * N + gcol] = acc[mi][ni][r] * escale + bvv;
      }
    }
}

// ---------------- ksum[bh][d] += partial sums of fp32 K (grid (8, BH), atomic) ----------------
__global__ __launch_bounds__(256) void ksum_part(
    const float* __restrict__ Kf, float* __restrict__ ksum) {
  __shared__ float red[4][64];
  const int t = threadIdx.x, d = t & 63, seg = t >> 6;
  const int bx = blockIdx.x, bh = blockIdx.y, b = bh >> 4, h = bh & 15;
  float s = 0.f;
  const int lbase = bx * 256 + seg * 64;
  for (int r = 0; r < 64; ++r)
    s += Kf[((size_t)b * Ln + lbase + r) * Dn + h * DHn + d];
  red[seg][d] = s;
  __syncthreads();
  if (t < 64) atomicAdd(&ksum[bh * DHn + t], red[0][t] + red[1][t] + red[2][t] + red[3][t]);
}

// ------- stats: f16 row max (MFMA) + exact mean; WIN=64 window refine fixes boundary -------
__global__ __launch_bounds__(256, 2) void attn_stats_mfma(
    const f16* __restrict__ Qh, const f16* __restrict__ Kh,
    const float* __restrict__ ksum,
    float* __restrict__ row_max, float* __restrict__ spars) {
  __shared__ f16 sQ[128 * 64], sK[128 * 64];
  __shared__ float redm[128][5];
  const int t = threadIdx.x;
  const int w = t >> 6, lane = t & 63, lm = lane & 15, q = lane >> 4;
  const int bh = blockIdx.y, b = bh >> 4, h = bh & 15;
  const int q0 = blockIdx.x * 128;
  const f16* qs = Qh + ((size_t)b * Ln + q0) * Dn + h * DHn;
#pragma unroll
  for (int c = 0; c < 4; ++c) {
    int f = (c * 256 + t) * 8; int row = f >> 6, col = f & 63;
    gl_lds16(qs + (size_t)row * Dn + col, &sQ[f]);
  }
  __syncthreads();
  f16x8 a_[8][2];
#pragma unroll
  for (int mi = 0; mi < 8; ++mi)
#pragma unroll
    for (int ks = 0; ks < 2; ++ks)
      a_[mi][ks] = *(const f16x8*)&sQ[(mi * 16 + lm) * 64 + ks * 32 + q * 8];
  float rmax[8][4];
#pragma unroll
  for (int mi = 0; mi < 8; ++mi)
#pragma unroll
    for (int r = 0; r < 4; ++r) rmax[mi][r] = -1e30f;

  for (int kt = 0; kt < Ln / 128; ++kt) {
    __syncthreads();
    const f16* ks_ = Kh + ((size_t)b * Ln + kt * 128) * Dn + h * DHn;
#pragma unroll
    for (int c = 0; c < 4; ++c) {
      int f = (c * 256 + t) * 8; int row = f >> 6, col = f & 63;
      gl_lds16(ks_ + (size_t)row * Dn + col, &sK[f]);
    }
    __syncthreads();
#pragma unroll
    for (int ni = 0; ni < 2; ++ni) {
      int bcol = (w * 2 + ni) * 16;
      f16x8 b_[2];
#pragma unroll
      for (int ks = 0; ks < 2; ++ks)
        b_[ks] = *(const f16x8*)&sK[(bcol + lm) * 64 + ks * 32 + q * 8];
#pragma unroll
      for (int mi = 0; mi < 8; ++mi) {
        f32x4 acc = {0.f, 0.f, 0.f, 0.f};
        acc = MFMA(a_[mi][0], b_[0], acc);
        acc = MFMA(a_[mi][1], b_[1], acc);
#pragma unroll
        for (int r = 0; r < 4; ++r) rmax[mi][r] = fmaxf(rmax[mi][r], acc[r]);
      }
    }
  }
#pragma unroll
  for (int mi = 0; mi < 8; ++mi)
#pragma unroll
    for (int r = 0; r < 4; ++r) {
      float v = rmax[mi][r];
      v = fmaxf(v, __shfl_xor(v, 1)); v = fmaxf(v, __shfl_xor(v, 2));
      v = fmaxf(v, __shfl_xor(v, 4)); v = fmaxf(v, __shfl_xor(v, 8));
      if (lm == 0) redm[mi * 16 + q * 4 + r][w] = v;
    }
  __syncthreads();
  if (t < 128) {
    float m = fmaxf(fmaxf(redm[t][0], redm[t][1]), fmaxf(redm[t][2], redm[t][3]));
    float dot = 0.f;
    const float* kp = ksum + bh * DHn;   // UNscaled fp32 sum of K
#pragma unroll
    for (int d = 0; d < 64; ++d)
      dot += (float)sQ[t * 64 + d] * kp[d];    // q' = q*16
    row_max[(size_t)bh * Ln + q0 + t] = m * PSC;
    spars[(size_t)bh * Ln + q0 + t] = m * PSC - dot * (SCALE / (16.0f * (float)Ln));
  }
}

// ---------------- bitonic sort, 1024 threads; bulk top + 64-row boundary window ----------------
__global__ __launch_bounds__(1024) void topk_sort(
    const float* __restrict__ spars, int* __restrict__ top_idx, int* __restrict__ wrow) {
  __shared__ unsigned long long keys[Ln];   // 16 KB
  const int t = threadIdx.x;
  const int bh = blockIdx.x;
  for (int i = t; i < Ln; i += 1024) {
    unsigned u = __float_as_uint(spars[(size_t)bh * Ln + i]);
    u = (u & 0x80000000u) ? ~u : (u | 0x80000000u);
    u = ~u;
    keys[i] = ((unsigned long long)u << 32) | (unsigned)i;
  }
  __syncthreads();
  for (int k = 2; k <= Ln; k <<= 1) {
    for (int j = k >> 1; j > 0; j >>= 1) {
      int i = ((t & ~(j - 1)) << 1) | (t & (j - 1));
      int ixj = i | j;
      unsigned long long a = keys[i], bb = keys[ixj];
      bool up = ((i & k) == 0);
      if ((a > bb) == up) { keys[i] = bb; keys[ixj] = a; }
      __syncthreads();
    }
  }
  for (int u = t; u < Un - WIN / 2; u += 1024)
    top_idx[(size_t)bh * Un + u] = (int)(keys[u] & 0xFFFFFFFFu);
  if (t < WIN) wrow[bh * WIN + t] = (int)(keys[Un - WIN / 2 + t] & 0xFFFFFFFFu);
}

// ------- exact fp32 q for window rows from x and Wq: qx[bh][win][64] -------
// grid (WIN/16, BHn). Thread: d = lane (wave-coalesced Wq reads), rg = wave (xs broadcast).
__global__ __launch_bounds__(256) void window_q(
    const float* __restrict__ x, const float* __restrict__ Wq, const float* __restrict__ bq,
    const int* __restrict__ wrow, float* __restrict__ qx) {
  __shared__ float xs[16][68];
  __shared__ int wr_[16];
  const int t = threadIdx.x;
  const int jg = blockIdx.x * 16;
  const int bh = blockIdx.y, b = bh >> 4, h = bh & 15;
  const int d = t & 63, rg = t >> 6;   // rg is wave-uniform
  if (t < 16) wr_[t] = wrow[bh * WIN + jg + t];
  __syncthreads();
  float acc[4] = {};
  for (int kc = 0; kc < Dn; kc += 64) {
    {
      int row = t >> 4, col = (t & 15) * 4;
      *(float4*)&xs[row][col] = *(const float4*)&x[((size_t)b * Ln + wr_[row]) * Dn + kc + col];
    }
    __syncthreads();
#pragma unroll 8
    for (int kk = 0; kk < 64; ++kk) {
      float wv = Wq[(size_t)(kc + kk) * Dn + h * DHn + d];
      acc[0] = fmaf(xs[rg * 4 + 0][kk], wv, acc[0]);
      acc[1] = fmaf(xs[rg * 4 + 1][kk], wv, acc[1]);
      acc[2] = fmaf(xs[rg * 4 + 2][kk], wv, acc[2]);
      acc[3] = fmaf(xs[rg * 4 + 3][kk], wv, acc[3]);
    }
    __syncthreads();
  }
  float bqs = bq[h * DHn + d];
#pragma unroll
  for (int rr = 0; rr < 4; ++rr)
    qx[((size_t)bh * WIN + jg + rg * 4 + rr) * 64 + d] = acc[rr] + bqs;
}

// ------- exact fp32 sparsity: 4 window rows per block, K streamed once through LDS -------
__global__ __launch_bounds__(256) void refine_rows(
    const float* __restrict__ qx, const float* __restrict__ Kf,
    float* __restrict__ spx) {
  __shared__ float qs[4][68];
  __shared__ float Ks[64][68];
  __shared__ float redm[4][64], reds[4][64];
  const int t = threadIdx.x;
  const int g = blockIdx.x, bh = blockIdx.y, b = bh >> 4, h = bh & 15;
  const int j = t & 3, s = t >> 2;
  {
    int jj = t >> 6, d = t & 63;
    qs[jj][d] = qx[((size_t)bh * WIN + g * 4 + jj) * 64 + d];
  }
  float mx = -1e30f, sm = 0.f;
  for (int kt = 0; kt < Ln / 64; ++kt) {
    __syncthreads();
#pragma unroll
    for (int c = 0; c < 4; ++c) {
      int idx = c * 256 + t;
      int krow = idx >> 4, kc4 = idx & 15;
      *(float4*)&Ks[krow][kc4 * 4] =
          *(const float4*)&Kf[((size_t)b * Ln + kt * 64 + krow) * Dn + h * DHn + kc4 * 4];
    }
    __syncthreads();
    float acc = 0.f;
#pragma unroll
    for (int c = 0; c < 16; ++c) {
      float4 k4 = *(const float4*)&Ks[s][c * 4];
      float4 q4 = *(const float4*)&qs[j][c * 4];
      acc = fmaf(k4.x, q4.x, acc);
      acc = fmaf(k4.y, q4.y, acc);
      acc = fmaf(k4.z, q4.z, acc);
      acc = fmaf(k4.w, q4.w, acc);
    }
    mx = fmaxf(mx, acc); sm += acc;
  }
  redm[j][s] = mx; reds[j][s] = sm;
  __syncthreads();
  if (t < 4) {
    float m = -1e30f, ssum = 0.f;
    for (int k = 0; k < 64; ++k) { m = fmaxf(m, redm[t][k]); ssum += reds[t][k]; }
    spx[bh * WIN + g * 4 + t] = SCALE * (m - ssum * (1.0f / (float)Ln));
  }
}

// ---------------- pick top-(WIN/2) of WIN window rows: rank-parallel, no big arrays ----------------
__global__ __launch_bounds__(64) void topk_final(
    const float* __restrict__ spx, const int* __restrict__ wrow,
    int* __restrict__ top_idx) {
  __shared__ float v[WIN];
  __shared__ int r[WIN];
  const int bh = blockIdx.x, j = threadIdx.x;
  v[j] = spx[bh * WIN + j];
  r[j] = wrow[bh * WIN + j];
  __syncthreads();
  int rank = 0;
  for (int i = 0; i < WIN; ++i)
    rank += (v[i] > v[j]) || (v[i] == v[j] && r[i] < r[j]);
  if (rank < WIN / 2) top_idx[(size_t)bh * Un + (Un - WIN / 2) + rank] = r[j];
}

// ------- selected-row attention, key-split x2: partial O (unnormalized) + denom -------
__global__ __launch_bounds__(256, 4) void attn_sel_part(
    const f16* __restrict__ Qh, const f16* __restrict__ Kh,
    const f16* __restrict__ Vth,
    const int* __restrict__ topi, const float* __restrict__ row_max,
    float* __restrict__ pO, float* __restrict__ pD) {
  __shared__ f16 sK[64 * 64], sV[64 * 64];
  __shared__ f16 sQP[64 * 80];   // Q staged (stride 80), then P (stride 80)
  __shared__ float rmL[64];
  __shared__ int qxL[64];
  __shared__ float dred[64][5];
  const int t = threadIdx.x;
  const int w = t >> 6, lane = t & 63, lm = lane & 15, q = lane >> 4;
  const int half = blockIdx.y & 1, bh = blockIdx.y >> 1, b = bh >> 4, h = bh & 15;
  const int u0 = blockIdx.x * 64;
  const int nrows = (Un - u0 < 64) ? (Un - u0) : 64;
  if (t < 64) {
    int qi = topi[(size_t)bh * Un + ((t < nrows) ? (u0 + t) : 0)];
    qxL[t] = qi;
    rmL[t] = row_max[(size_t)bh * Ln + qi];
  }
  __syncthreads();
#pragma unroll
  for (int c = 0; c < 2; ++c) {
    int f = (c * 256 + t) * 8; int row = f >> 6, col = f & 63;
    size_t go = ((size_t)b * Ln + qxL[row]) * Dn + h * DHn + col;
    *(uint4*)&sQP[row * 80 + col] = *(const uint4*)&Qh[go];
  }
  __syncthreads();
  f16x8 aq[4][2];
#pragma unroll
  for (int mi = 0; mi < 4; ++mi)
#pragma unroll
    for (int ks = 0; ks < 2; ++ks)
      aq[mi][ks] = *(const f16x8*)&sQP[(mi * 16 + lm) * 80 + ks * 32 + q * 8];
  f32x4 oacc[4] = {};
  float dacc[4][4] = {};

  const f16* kbase = Kh + (size_t)b * Ln * Dn + h * DHn;
  const f16* vbase = Vth + (size_t)bh * DHn * Ln;
  for (int kt = 0; kt < 16; ++kt) {
    const int l0 = half * 1024 + kt * 64;
    __syncthreads();
#pragma unroll
    for (int c = 0; c < 2; ++c) {
      int f = (c * 256 + t) * 8; int row = f >> 6, col = f & 63;
      gl_lds16(kbase + (size_t)(l0 + row) * Dn + col, &sK[f]);
      gl_lds16(vbase + (size_t)row * Ln + l0 + col, &sV[f]);
    }
    __syncthreads();
    f16x8 kb[2];
#pragma unroll
    for (int ks = 0; ks < 2; ++ks)
      kb[ks] = *(const f16x8*)&sK[(w * 16 + lm) * 64 + ks * 32 + q * 8];
#pragma unroll
    for (int mi = 0; mi < 4; ++mi) {
      f32x4 acc = {0.f, 0.f, 0.f, 0.f};
      acc = MFMA(aq[mi][0], kb[0], acc);
      acc = MFMA(aq[mi][1], kb[1], acc);
#pragma unroll
      for (int r = 0; r < 4; ++r) {
        int row = mi * 16 + q * 4 + r;
        float p = __expf(acc[r] * PSC - rmL[row]);
        dacc[mi][r] += p;
        sQP[row * 80 + w * 16 + lm] = (f16)(p * SPf);
      }
    }
    __syncthreads();
    f16x8 vb[2];
#pragma unroll
    for (int ks = 0; ks < 2; ++ks)
      vb[ks] = *(const f16x8*)&sV[(w * 16 + lm) * 64 + ks * 32 + q * 8];
#pragma unroll
    for (int mi = 0; mi < 4; ++mi) {
#pragma unroll
      for (int ks = 0; ks < 2; ++ks) {
        f16x8 pf = *(const f16x8*)&sQP[(mi * 16 + lm) * 80 + ks * 32 + q * 8];
        oacc[mi] = MFMA(pf, vb[ks], oacc[mi]);
      }
    }
  }
#pragma unroll
  for (int mi = 0; mi < 4; ++mi)
#pragma unroll
    for (int r = 0; r < 4; ++r) {
      float v = dacc[mi][r];
      v += __shfl_xor(v, 1); v += __shfl_xor(v, 2);
      v += __shfl_xor(v, 4); v += __shfl_xor(v, 8);
      if (lm == 0) dred[mi * 16 + q * 4 + r][w] = v;
    }
  __syncthreads();
  const size_t pbase = ((size_t)half * BHn + bh) * 1280 + u0;
  if (t < 64)
    pD[pbase + t] = dred[t][0] + dred[t][1] + dred[t][2] + dred[t][3];
#pragma unroll
  for (int mi = 0; mi < 4; ++mi)
#pragma unroll
    for (int r = 0; r < 4; ++r) {
      int row = mi * 16 + q * 4 + r;
      pO[(pbase + row) * 64 + w * 16 + lm] = oacc[mi][r];
    }
}

// ---------------- combine halves, normalize, scatter to AOh ----------------
__global__ __launch_bounds__(256) void attn_combine(
    const float* __restrict__ pO, const float* __restrict__ pD,
    const int* __restrict__ topi, f16* __restrict__ AOh) {
  const int t = threadIdx.x;
  const int u0 = blockIdx.x * 64, bh = blockIdx.y, b = bh >> 4, h = bh & 15;
  const int nrows = (Un - u0 < 64) ? (Un - u0) : 64;
  const int row = t >> 2, pg = t & 3;
  if (row >= nrows) return;
  int qi = topi[(size_t)bh * Un + u0 + row];
  size_t i0 = (size_t)bh * 1280 + u0 + row;
  size_t i1 = (size_t)BHn * 1280 + i0;
  float dinv = 1.0f / (pD[i0] + pD[i1]);
  const float* p0 = &pO[i0 * 64 + pg * 16];
  const float* p1 = &pO[i1 * 64 + pg * 16];
  f16 buf[16];
#pragma unroll
  for (int c = 0; c < 4; ++c) {
    float4 a = *(const float4*)&p0[c * 4];
    float4 bb = *(const float4*)&p1[c * 4];
    buf[c * 4 + 0] = (f16)((a.x + bb.x) * dinv);
    buf[c * 4 + 1] = (f16)((a.y + bb.y) * dinv);
    buf[c * 4 + 2] = (f16)((a.z + bb.z) * dinv);
    buf[c * 4 + 3] = (f16)((a.w + bb.w) * dinv);
  }
  f16* dst = &AOh[((size_t)b * Ln + qi) * Dn + h * DHn + pg * 16];
  *(uint4*)&dst[0] = *(uint4*)&buf[0];
  *(uint4*)&dst[8] = *(uint4*)&buf[8];
}

extern "C" void kernel_launch(void* const* d_in, const int* in_sizes, int n_in,
                              void* d_out, int out_size, void* d_ws, size_t ws_size,
                              hipStream_t stream) {
  (void)in_sizes; (void)n_in; (void)out_size; (void)ws_size;
  const float* x  = (const float*)d_in[0];
  const float* Wq = (const float*)d_in[1];
  const float* bq = (const float*)d_in[2];
  const float* Wk = (const float*)d_in[3];
  const float* bk = (const float*)d_in[4];
  const float* Wv = (const float*)d_in[5];
  const float* bv = (const float*)d_in[6];
  const float* Wo = (const float*)d_in[7];
  const float* bo = (const float*)d_in[8];
  float* out = (float*)d_out;

  uint8_t* p = (uint8_t*)d_ws;
  const size_t NE = (size_t)Bn * Ln * Dn;          // 4 Mi elements
  f16* xh = (f16*)p;  p += NE * 2;
  f16* xl = (f16*)p;  p += NE * 2;
  f16* Wt_h = (f16*)p; p += (size_t)4096 * Dn * 2;   // rows 0-3071: QKV cat; 3072-4095: Wo
  f16* Wt_l = (f16*)p; p += (size_t)4096 * Dn * 2;   // only rows 1024-2047 (Wk) populated
  f16* Qbh = (f16*)p; p += NE * 2;
  f16* Kbh = (f16*)p; p += NE * 2;
  float* Kf = (float*)p;  p += NE * 4;
  f16* Vh16 = (f16*)p; p += NE * 2;
  f16* Vth  = (f16*)p; p += NE * 2;
  float* rowmax = (float*)p; p += (size_t)BHn * Ln * 4;
  float* spars  = (float*)p; p += (size_t)BHn * Ln * 4;
  float* ksum   = (float*)p; p += (size_t)BHn * DHn * 4;
  int* topi     = (int*)p;   p += (size_t)BHn * Un * 4;
  int* wrow     = (int*)p;   p += (size_t)BHn * WIN * 4;
  float* spx    = (float*)p; p += (size_t)BHn * WIN * 4;
  float* qx     = (float*)p; p += (size_t)BHn * WIN * 64 * 4;
  float* pD     = (float*)p; p += (size_t)2 * BHn * 1280 * 4;
  float* pO     = (float*)p; p += (size_t)2 * BHn * 1280 * 64 * 4;
  f16* AOh = xh;   // alias: x split dead after QKV GEMM

  dim3 blk(256);
  hipLaunchKernelGGL(split_kernel, dim3((int)(NE / 4 / 256)), blk, 0, stream, x, xh, xl, (int)(NE / 4));
  hipLaunchKernelGGL(tsplit_w4, dim3(16, 16, 4), blk, 0, stream, Wq, Wk, Wv, Wo, Wt_h, Wt_l);
  hipLaunchKernelGGL(gemm_qkv, dim3(24, 32), blk, 0, stream, xh, xl, Wt_h, Wt_l,
                     bq, bk, bv, Qbh, Kf, Kbh, Vh16, Dn);
  hipLaunchKernelGGL(tsplit_v, dim3(Ln / 64, BHn), blk, 0, stream, Vh16, Vth);
  hipMemsetAsync(ksum, 0, (size_t)BHn * DHn * 4, stream);
  hipLaunchKernelGGL(ksum_part, dim3(8, BHn), blk, 0, stream, Kf, ksum);
  hipLaunchKernelGGL(attn_stats_mfma, dim3(Ln / 128, BHn), blk, 0, stream,
                     Qbh, Kbh, ksum, rowmax, spars);
  hipLaunchKernelGGL(topk_sort, dim3(BHn), dim3(1024), 0, stream, spars, topi, wrow);
  hipLaunchKernelGGL(window_q, dim3(WIN / 16, BHn), blk, 0, stream, x, Wq, bq, wrow, qx);
  hipLaunchKernelGGL(refine_rows, dim3(WIN / 4, BHn), blk, 0, stream, qx, Kf, spx);
  hipLaunchKernelGGL(topk_final, dim3(BHn), dim3(WIN), 0, stream, spx, wrow, topi);
  hipMemsetAsync(AOh, 0, NE * 2, stream);
  hipLaunchKernelGGL(attn_sel_part, dim3((Un + 63) / 64, 2 * BHn), blk, 0, stream,
                     Qbh, Kbh, Vth, topi, rowmax, pO, pD);
  hipLaunchKernelGGL(attn_combine, dim3((Un + 63) / 64, BHn), blk, 0, stream,
                     pO, pD, topi, AOh);
  hipLaunchKernelGGL(gemm_a1, dim3(16, 32), blk, 0, stream, AOh,
                     Wt_h + (size_t)3072 * Dn, bo, ESC_OUT, out, Bn * Ln, Dn, Dn);
}

// Round 10
// 409.481 us; speedup vs baseline: 2.2553x; 2.2553x over previous
//
#include <hip/hip_runtime.h>
#include <math.h>
#include <stdint.h>

#define Bn 2
#define Ln 2048
#define Dn 1024
#define Hn 16
#define DHn 64
#define Un 1228
#define BHn (Bn*Hn)
#define WIN 64                       // exact-refine window: ranks [U-32, U+32)
#define SCALE 0.125f
// pre-split power-of-2 scales (dodge fp16 subnormal flush on lo terms)
#define SXf 16.0f     // x
#define SWf 256.0f    // all W
#define SQf 16.0f     // Q, K
#define SVf 16.0f     // V
#define SPf 16.0f     // softmax P
#define ESC_PROJ (1.0f / 4096.0f)    // 1/(SX*SW)
#define ESC_OUT  (1.0f / 65536.0f)   // 1/(SPf*SVf*SWf)
#define PSC (SCALE / 256.0f)         // score unscale: 1/(SQ*SQ) * SCALE

typedef _Float16 f16;
typedef __attribute__((ext_vector_type(8))) _Float16 f16x8;
typedef __attribute__((ext_vector_type(4))) float f32x4;
struct h4s { f16 x, y, z, w; };

__device__ __forceinline__ void splitf16(float f, f16& hi, f16& lo) {
  hi = (f16)f;                 // RTNE
  lo = (f16)(f - (float)hi);   // residual, ~22 mantissa bits total
}

// async global->LDS, 16B per lane (wave-uniform base + lane*16)
__device__ __forceinline__ void gl_lds16(const void* g, void* l) {
  __builtin_amdgcn_global_load_lds(
      (const __attribute__((address_space(1))) void*)g,
      (__attribute__((address_space(3))) void*)l, 16, 0, 0);
}

#define MFMA(a, b, c) __builtin_amdgcn_mfma_f32_16x16x32_f16((a), (b), (c), 0, 0, 0)

// ---------------- split x*16 -> xh, xl ----------------
__global__ __launch_bounds__(256) void split_kernel(
    const float* __restrict__ in, f16* __restrict__ oh, f16* __restrict__ ol, int n4) {
  int i = blockIdx.x * 256 + threadIdx.x;
  if (i >= n4) return;
  float4 v = ((const float4*)in)[i];
  h4s h, l;
  splitf16(v.x * SXf, h.x, l.x); splitf16(v.y * SXf, h.y, l.y);
  splitf16(v.z * SXf, h.z, l.z); splitf16(v.w * SXf, h.w, l.w);
  ((h4s*)oh)[i] = h; ((h4s*)ol)[i] = l;
}

// ------- transpose + split W*256 for all 4 weights: Wt[z*1024 + n][k]; lo only for Wk -------
__global__ __launch_bounds__(256) void tsplit_w4(
    const float* __restrict__ W0, const float* __restrict__ W1,
    const float* __restrict__ W2, const float* __restrict__ W3,
    f16* __restrict__ oh, f16* __restrict__ ol) {
  __shared__ float ts[64][65];
  const int t = threadIdx.x;
  const int r0 = blockIdx.x * 64, c0 = blockIdx.y * 64;
  const int z = blockIdx.z;
  const float* in = (z == 0) ? W0 : (z == 1) ? W1 : (z == 2) ? W2 : W3;
#pragma unroll
  for (int c = 0; c < 4; ++c) {
    int f = (c * 256 + t) * 4; int row = f >> 6, col = f & 63;
    float4 v = *(const float4*)&in[(size_t)(r0 + row) * Dn + c0 + col];
    ts[row][col] = v.x; ts[row][col + 1] = v.y; ts[row][col + 2] = v.z; ts[row][col + 3] = v.w;
  }
  __syncthreads();
#pragma unroll
  for (int c = 0; c < 4; ++c) {
    int f = (c * 256 + t) * 4; int crow = f >> 6, rcol = f & 63;
    h4s h, l;
    splitf16(ts[rcol + 0][crow] * SWf, h.x, l.x);
    splitf16(ts[rcol + 1][crow] * SWf, h.y, l.y);
    splitf16(ts[rcol + 2][crow] * SWf, h.z, l.z);
    splitf16(ts[rcol + 3][crow] * SWf, h.w, l.w);
    size_t o = (size_t)(z * 1024 + c0 + crow) * Dn + r0 + rcol;
    *(h4s*)&oh[o] = h;
    if (z == 1) *(h4s*)&ol[o] = l;     // lo needed only for Wk (3-MFMA K segment)
  }
}

// ------- Q+V projection, 1-MFMA: grid (16,32); bx 0-7 Q, 8-15 V. No branch in K-loop. -------
__global__ __launch_bounds__(256) void gemm_qv(
    const f16* __restrict__ Ah, const f16* __restrict__ Bth,
    const float* __restrict__ bq, const float* __restrict__ bv,
    f16* __restrict__ Qbh, f16* __restrict__ Vh16, int K) {
  __shared__ f16 sA[128 * 32], sB[128 * 32];
  const int t = threadIdx.x;
  const int w = t >> 6, lane = t & 63, lm = lane & 15, q = lane >> 4;
  const int wr = w >> 1, wc = w & 1;
  const int seg = blockIdx.x >> 3;                 // 0=Q, 1=V
  const int nloc = (blockIdx.x & 7) * 128;         // col within segment
  const int brow = (seg ? 2048 : 0) + nloc;        // row in concatenated Wt
  const int m0 = blockIdx.y * 128;
  f32x4 acc[4][4] = {};
  for (int k0 = 0; k0 < K; k0 += 32) {
    const f16* s0 = Ah + (size_t)m0 * K + k0;
    const f16* s2 = Bth + (size_t)brow * K + k0;
#pragma unroll
    for (int c = 0; c < 2; ++c) {
      int f = (c * 256 + t) * 8; int row = f >> 5, col = f & 31;
      size_t go = (size_t)row * K + col;
      gl_lds16(s0 + go, &sA[f]);
      gl_lds16(s2 + go, &sB[f]);
    }
    __syncthreads();
    f16x8 a_[4], b_[4];
#pragma unroll
    for (int mi = 0; mi < 4; ++mi)
      a_[mi] = *(const f16x8*)&sA[(wr * 64 + mi * 16 + lm) * 32 + q * 8];
#pragma unroll
    for (int ni = 0; ni < 4; ++ni)
      b_[ni] = *(const f16x8*)&sB[(wc * 64 + ni * 16 + lm) * 32 + q * 8];
#pragma unroll
    for (int mi = 0; mi < 4; ++mi)
#pragma unroll
      for (int ni = 0; ni < 4; ++ni)
        acc[mi][ni] = MFMA(a_[mi], b_[ni], acc[mi][ni]);
    __syncthreads();
  }
  const float* bp = seg ? bv : bq;
  f16* outp = seg ? Vh16 : Qbh;      // SQf == SVf == 16, so scale is uniform
#pragma unroll
  for (int mi = 0; mi < 4; ++mi)
#pragma unroll
    for (int ni = 0; ni < 4; ++ni) {
      int c = nloc + wc * 64 + ni * 16 + lm;
      float bvv = bp[c];
#pragma unroll
      for (int r = 0; r < 4; ++r) {
        int grow = m0 + wr * 64 + mi * 16 + q * 4 + r;
        float v = acc[mi][ni][r] * ESC_PROJ + bvv;
        outp[(size_t)grow * 1024 + c] = (f16)(v * SQf);
      }
    }
}

// ------- K projection, 3-MFMA split (round-8 proven body): grid (8,32) -------
__global__ void gemm_k(
    const f16* __restrict__ Ah, const f16* __restrict__ Al,
    const f16* __restrict__ Bth, const f16* __restrict__ Btl,
    const float* __restrict__ bk,
    float* __restrict__ Kf, f16* __restrict__ Kbh, int K) {
  __shared__ f16 sAh[128 * 32], sAl[128 * 32], sBh[128 * 32], sBl[128 * 32];
  const int t = threadIdx.x;
  const int w = t >> 6, lane = t & 63, lm = lane & 15, q = lane >> 4;
  const int wr = w >> 1, wc = w & 1;
  const int nloc = blockIdx.x * 128;
  const int brow = 1024 + nloc;                    // Wk rows in concatenated Wt
  const int m0 = blockIdx.y * 128;
  f32x4 acc[4][4] = {};
  for (int k0 = 0; k0 < K; k0 += 32) {
    const f16* s0 = Ah + (size_t)m0 * K + k0;
    const f16* s1 = Al + (size_t)m0 * K + k0;
    const f16* s2 = Bth + (size_t)brow * K + k0;
    const f16* s3 = Btl + (size_t)brow * K + k0;
#pragma unroll
    for (int c = 0; c < 2; ++c) {
      int f = (c * 256 + t) * 8; int row = f >> 5, col = f & 31;
      size_t go = (size_t)row * K + col;
      gl_lds16(s0 + go, &sAh[f]);
      gl_lds16(s1 + go, &sAl[f]);
      gl_lds16(s2 + go, &sBh[f]);
      gl_lds16(s3 + go, &sBl[f]);
    }
    __syncthreads();
    f16x8 a_h[4], a_l[4], b_h[4], b_l[4];
#pragma unroll
    for (int mi = 0; mi < 4; ++mi) {
      int r = (wr * 64 + mi * 16 + lm) * 32 + q * 8;
      a_h[mi] = *(const f16x8*)&sAh[r];
      a_l[mi] = *(const f16x8*)&sAl[r];
    }
#pragma unroll
    for (int ni = 0; ni < 4; ++ni) {
      int r = (wc * 64 + ni * 16 + lm) * 32 + q * 8;
      b_h[ni] = *(const f16x8*)&sBh[r];
      b_l[ni] = *(const f16x8*)&sBl[r];
    }
#pragma unroll
    for (int mi = 0; mi < 4; ++mi)
#pragma unroll
      for (int ni = 0; ni < 4; ++ni) {
        acc[mi][ni] = MFMA(a_h[mi], b_h[ni], acc[mi][ni]);
        acc[mi][ni] = MFMA(a_h[mi], b_l[ni], acc[mi][ni]);
        acc[mi][ni] = MFMA(a_l[mi], b_h[ni], acc[mi][ni]);
      }
    __syncthreads();
  }
#pragma unroll
  for (int mi = 0; mi < 4; ++mi)
#pragma unroll
    for (int ni = 0; ni < 4; ++ni) {
      int c = nloc + wc * 64 + ni * 16 + lm;
      float bvv = bk[c];
#pragma unroll
      for (int r = 0; r < 4; ++r) {
        int grow = m0 + wr * 64 + mi * 16 + q * 4 + r;
        float v = acc[mi][ni][r] * ESC_PROJ + bvv;
        size_t o = (size_t)grow * 1024 + c;
        Kf[o] = v;
        Kbh[o] = (f16)(v * SQf);
      }
    }
}

// ---------------- transpose V (f16): Vh16[b,l,D] -> Vt[bh*64+d][L] ----------------
__global__ __launch_bounds__(256) void tsplit_v(
    const f16* __restrict__ Vh16, f16* __restrict__ out) {
  __shared__ f16 ts[64][72];
  const int t = threadIdx.x;
  const int l0 = blockIdx.x * 64;
  const int bh = blockIdx.y, b = bh >> 4, h = bh & 15;
#pragma unroll
  for (int c = 0; c < 2; ++c) {
    int e = c * 256 + t; int row = e >> 3, cg = e & 7;
    *(uint4*)&ts[row][cg * 8] =
        *(const uint4*)&Vh16[((size_t)b * Ln + l0 + row) * Dn + h * DHn + cg * 8];
  }
  __syncthreads();
#pragma unroll
  for (int c = 0; c < 2; ++c) {
    int e = c * 256 + t; int drow = e >> 3, lg = e & 7;
    f16 tmp[8];
#pragma unroll
    for (int j = 0; j < 8; ++j) tmp[j] = ts[lg * 8 + j][drow];
    *(uint4*)&out[((size_t)bh * DHn + drow) * Ln + l0 + lg * 8] = *(uint4*)tmp;
  }
}

// ---------------- out-proj GEMM, 1-MFMA (A f16, B f16): 128x64 tiles ----------------
__global__ __launch_bounds__(256, 4) void gemm_a1(
    const f16* __restrict__ A, const f16* __restrict__ Bth,
    const float* __restrict__ bias, float escale,
    float* __restrict__ Cf, int M, int N, int K) {
  __shared__ f16 sA[128 * 32], sB[64 * 32];
  const int t = threadIdx.x;
  const int w = t >> 6, lane = t & 63, lm = lane & 15, q = lane >> 4;
  const int wr = w >> 1, wc = w & 1;
  const int n0 = blockIdx.x * 64, m0 = blockIdx.y * 128;
  f32x4 acc[4][2] = {};
  for (int k0 = 0; k0 < K; k0 += 32) {
    const f16* s0 = A + (size_t)m0 * K + k0;
    const f16* s2 = Bth + (size_t)n0 * K + k0;
#pragma unroll
    for (int c = 0; c < 2; ++c) {
      int f = (c * 256 + t) * 8; int row = f >> 5, col = f & 31;
      gl_lds16(s0 + (size_t)row * K + col, &sA[f]);
    }
    {
      int f = t * 8; int row = f >> 5, col = f & 31;
      gl_lds16(s2 + (size_t)row * K + col, &sB[f]);
    }
    __syncthreads();
    f16x8 a_[4], b_[2];
#pragma unroll
    for (int mi = 0; mi < 4; ++mi)
      a_[mi] = *(const f16x8*)&sA[(wr * 64 + mi * 16 + lm) * 32 + q * 8];
#pragma unroll
    for (int ni = 0; ni < 2; ++ni)
      b_[ni] = *(const f16x8*)&sB[(wc * 32 + ni * 16 + lm) * 32 + q * 8];
#pragma unroll
    for (int mi = 0; mi < 4; ++mi)
#pragma unroll
      for (int ni = 0; ni < 2; ++ni)
        acc[mi][ni] = MFMA(a_[mi], b_[ni], acc[mi][ni]);
    __syncthreads();
  }
#pragma unroll
  for (int mi = 0; mi < 4; ++mi)
#pragma unroll
    for (int ni = 0; ni < 2; ++ni) {
      int gcol = n0 + wc * 32 + ni * 16 + lm;
      float bvv = bias[gcol];
#pragma unroll
      for (int r = 0; r < 4; ++r) {
        int grow = m0 + wr * 64 + mi * 16 + q * 4 + r;
        Cf[(size_t)grow * N + gcol] = acc[mi][ni][r] * escale + bvv;
      }
    }
}

// ---------------- ksum[bh][d] += partial sums of fp32 K (grid (8, BH), atomic) ----------------
__global__ __launch_bounds__(256) void ksum_part(
    const float* __restrict__ Kf, float* __restrict__ ksum) {
  __shared__ float red[4][64];
  const int t = threadIdx.x, d = t & 63, seg = t >> 6;
  const int bx = blockIdx.x, bh = blockIdx.y, b = bh >> 4, h = bh & 15;
  float s = 0.f;
  const int lbase = bx * 256 + seg * 64;
  for (int r = 0; r < 64; ++r)
    s += Kf[((size_t)b * Ln + lbase + r) * Dn + h * DHn + d];
  red[seg][d] = s;
  __syncthreads();
  if (t < 64) atomicAdd(&ksum[bh * DHn + t], red[0][t] + red[1][t] + red[2][t] + red[3][t]);
}

// ------- stats: f16 row max (MFMA) + exact mean; WIN=64 window refine fixes boundary -------
__global__ __launch_bounds__(256, 2) void attn_stats_mfma(
    const f16* __restrict__ Qh, const f16* __restrict__ Kh,
    const float* __restrict__ ksum,
    float* __restrict__ row_max, float* __restrict__ spars) {
  __shared__ f16 sQ[128 * 64], sK[128 * 64];
  __shared__ float redm[128][5];
  const int t = threadIdx.x;
  const int w = t >> 6, lane = t & 63, lm = lane & 15, q = lane >> 4;
  const int bh = blockIdx.y, b = bh >> 4, h = bh & 15;
  const int q0 = blockIdx.x * 128;
  const f16* qs = Qh + ((size_t)b * Ln + q0) * Dn + h * DHn;
#pragma unroll
  for (int c = 0; c < 4; ++c) {
    int f = (c * 256 + t) * 8; int row = f >> 6, col = f & 63;
    gl_lds16(qs + (size_t)row * Dn + col, &sQ[f]);
  }
  __syncthreads();
  f16x8 a_[8][2];
#pragma unroll
  for (int mi = 0; mi < 8; ++mi)
#pragma unroll
    for (int ks = 0; ks < 2; ++ks)
      a_[mi][ks] = *(const f16x8*)&sQ[(mi * 16 + lm) * 64 + ks * 32 + q * 8];
  float rmax[8][4];
#pragma unroll
  for (int mi = 0; mi < 8; ++mi)
#pragma unroll
    for (int r = 0; r < 4; ++r) rmax[mi][r] = -1e30f;

  for (int kt = 0; kt < Ln / 128; ++kt) {
    __syncthreads();
    const f16* ks_ = Kh + ((size_t)b * Ln + kt * 128) * Dn + h * DHn;
#pragma unroll
    for (int c = 0; c < 4; ++c) {
      int f = (c * 256 + t) * 8; int row = f >> 6, col = f & 63;
      gl_lds16(ks_ + (size_t)row * Dn + col, &sK[f]);
    }
    __syncthreads();
#pragma unroll
    for (int ni = 0; ni < 2; ++ni) {
      int bcol = (w * 2 + ni) * 16;
      f16x8 b_[2];
#pragma unroll
      for (int ks = 0; ks < 2; ++ks)
        b_[ks] = *(const f16x8*)&sK[(bcol + lm) * 64 + ks * 32 + q * 8];
#pragma unroll
      for (int mi = 0; mi < 8; ++mi) {
        f32x4 acc = {0.f, 0.f, 0.f, 0.f};
        acc = MFMA(a_[mi][0], b_[0], acc);
        acc = MFMA(a_[mi][1], b_[1], acc);
#pragma unroll
        for (int r = 0; r < 4; ++r) rmax[mi][r] = fmaxf(rmax[mi][r], acc[r]);
      }
    }
  }
#pragma unroll
  for (int mi = 0; mi < 8; ++mi)
#pragma unroll
    for (int r = 0; r < 4; ++r) {
      float v = rmax[mi][r];
      v = fmaxf(v, __shfl_xor(v, 1)); v = fmaxf(v, __shfl_xor(v, 2));
      v = fmaxf(v, __shfl_xor(v, 4)); v = fmaxf(v, __shfl_xor(v, 8));
      if (lm == 0) redm[mi * 16 + q * 4 + r][w] = v;
    }
  __syncthreads();
  if (t < 128) {
    float m = fmaxf(fmaxf(redm[t][0], redm[t][1]), fmaxf(redm[t][2], redm[t][3]));
    float dot = 0.f;
    const float* kp = ksum + bh * DHn;   // UNscaled fp32 sum of K
#pragma unroll
    for (int d = 0; d < 64; ++d)
      dot += (float)sQ[t * 64 + d] * kp[d];    // q' = q*16
    row_max[(size_t)bh * Ln + q0 + t] = m * PSC;
    spars[(size_t)bh * Ln + q0 + t] = m * PSC - dot * (SCALE / (16.0f * (float)Ln));
  }
}

// ---------------- bitonic sort, 1024 threads; bulk top + 64-row boundary window ----------------
__global__ __launch_bounds__(1024) void topk_sort(
    const float* __restrict__ spars, int* __restrict__ top_idx, int* __restrict__ wrow) {
  __shared__ unsigned long long keys[Ln];   // 16 KB
  const int t = threadIdx.x;
  const int bh = blockIdx.x;
  for (int i = t; i < Ln; i += 1024) {
    unsigned u = __float_as_uint(spars[(size_t)bh * Ln + i]);
    u = (u & 0x80000000u) ? ~u : (u | 0x80000000u);
    u = ~u;
    keys[i] = ((unsigned long long)u << 32) | (unsigned)i;
  }
  __syncthreads();
  for (int k = 2; k <= Ln; k <<= 1) {
    for (int j = k >> 1; j > 0; j >>= 1) {
      int i = ((t & ~(j - 1)) << 1) | (t & (j - 1));
      int ixj = i | j;
      unsigned long long a = keys[i], bb = keys[ixj];
      bool up = ((i & k) == 0);
      if ((a > bb) == up) { keys[i] = bb; keys[ixj] = a; }
      __syncthreads();
    }
  }
  for (int u = t; u < Un - WIN / 2; u += 1024)
    top_idx[(size_t)bh * Un + u] = (int)(keys[u] & 0xFFFFFFFFu);
  if (t < WIN) wrow[bh * WIN + t] = (int)(keys[Un - WIN / 2 + t] & 0xFFFFFFFFu);
}

// ------- exact fp32 q for window rows from x and Wq: qx[bh][win][64] -------
__global__ __launch_bounds__(256) void window_q(
    const float* __restrict__ x, const float* __restrict__ Wq, const float* __restrict__ bq,
    const int* __restrict__ wrow, float* __restrict__ qx) {
  __shared__ float xs[16][68];
  __shared__ int wr_[16];
  const int t = threadIdx.x;
  const int jg = blockIdx.x * 16;
  const int bh = blockIdx.y, b = bh >> 4, h = bh & 15;
  const int d = t & 63, rg = t >> 6;   // rg is wave-uniform
  if (t < 16) wr_[t] = wrow[bh * WIN + jg + t];
  __syncthreads();
  float acc[4] = {};
  for (int kc = 0; kc < Dn; kc += 64) {
    {
      int row = t >> 4, col = (t & 15) * 4;
      *(float4*)&xs[row][col] = *(const float4*)&x[((size_t)b * Ln + wr_[row]) * Dn + kc + col];
    }
    __syncthreads();
#pragma unroll 8
    for (int kk = 0; kk < 64; ++kk) {
      float wv = Wq[(size_t)(kc + kk) * Dn + h * DHn + d];
      acc[0] = fmaf(xs[rg * 4 + 0][kk], wv, acc[0]);
      acc[1] = fmaf(xs[rg * 4 + 1][kk], wv, acc[1]);
      acc[2] = fmaf(xs[rg * 4 + 2][kk], wv, acc[2]);
      acc[3] = fmaf(xs[rg * 4 + 3][kk], wv, acc[3]);
    }
    __syncthreads();
  }
  float bqs = bq[h * DHn + d];
#pragma unroll
  for (int rr = 0; rr < 4; ++rr)
    qx[((size_t)bh * WIN + jg + rg * 4 + rr) * 64 + d] = acc[rr] + bqs;
}

// ------- exact fp32 sparsity: 4 window rows per block, K streamed once through LDS -------
__global__ __launch_bounds__(256) void refine_rows(
    const float* __restrict__ qx, const float* __restrict__ Kf,
    float* __restrict__ spx) {
  __shared__ float qs[4][68];
  __shared__ float Ks[64][68];
  __shared__ float redm[4][64], reds[4][64];
  const int t = threadIdx.x;
  const int g = blockIdx.x, bh = blockIdx.y, b = bh >> 4, h = bh & 15;
  const int j = t & 3, s = t >> 2;
  {
    int jj = t >> 6, d = t & 63;
    qs[jj][d] = qx[((size_t)bh * WIN + g * 4 + jj) * 64 + d];
  }
  float mx = -1e30f, sm = 0.f;
  for (int kt = 0; kt < Ln / 64; ++kt) {
    __syncthreads();
#pragma unroll
    for (int c = 0; c < 4; ++c) {
      int idx = c * 256 + t;
      int krow = idx >> 4, kc4 = idx & 15;
      *(float4*)&Ks[krow][kc4 * 4] =
          *(const float4*)&Kf[((size_t)b * Ln + kt * 64 + krow) * Dn + h * DHn + kc4 * 4];
    }
    __syncthreads();
    float acc = 0.f;
#pragma unroll
    for (int c = 0; c < 16; ++c) {
      float4 k4 = *(const float4*)&Ks[s][c * 4];
      float4 q4 = *(const float4*)&qs[j][c * 4];
      acc = fmaf(k4.x, q4.x, acc);
      acc = fmaf(k4.y, q4.y, acc);
      acc = fmaf(k4.z, q4.z, acc);
      acc = fmaf(k4.w, q4.w, acc);
    }
    mx = fmaxf(mx, acc); sm += acc;
  }
  redm[j][s] = mx; reds[j][s] = sm;
  __syncthreads();
  if (t < 4) {
    float m = -1e30f, ssum = 0.f;
    for (int k = 0; k < 64; ++k) { m = fmaxf(m, redm[t][k]); ssum += reds[t][k]; }
    spx[bh * WIN + g * 4 + t] = SCALE * (m - ssum * (1.0f / (float)Ln));
  }
}

// ---------------- pick top-(WIN/2) of WIN window rows: rank-parallel ----------------
__global__ __launch_bounds__(64) void topk_final(
    const float* __restrict__ spx, const int* __restrict__ wrow,
    int* __restrict__ top_idx) {
  __shared__ float v[WIN];
  __shared__ int r[WIN];
  const int bh = blockIdx.x, j = threadIdx.x;
  v[j] = spx[bh * WIN + j];
  r[j] = wrow[bh * WIN + j];
  __syncthreads();
  int rank = 0;
  for (int i = 0; i < WIN; ++i)
    rank += (v[i] > v[j]) || (v[i] == v[j] && r[i] < r[j]);
  if (rank < WIN / 2) top_idx[(size_t)bh * Un + (Un - WIN / 2) + rank] = r[j];
}

// ------- selected-row attention, key-split x2: partial O (unnormalized) + denom -------
__global__ __launch_bounds__(256, 4) void attn_sel_part(
    const f16* __restrict__ Qh, const f16* __restrict__ Kh,
    const f16* __restrict__ Vth,
    const int* __restrict__ topi, const float* __restrict__ row_max,
    float* __restrict__ pO, float* __restrict__ pD) {
  __shared__ f16 sK[64 * 64], sV[64 * 64];
  __shared__ f16 sQP[64 * 80];   // Q staged (stride 80), then P (stride 80)
  __shared__ float rmL[64];
  __shared__ int qxL[64];
  __shared__ float dred[64][5];
  const int t = threadIdx.x;
  const int w = t >> 6, lane = t & 63, lm = lane & 15, q = lane >> 4;
  const int half = blockIdx.y & 1, bh = blockIdx.y >> 1, b = bh >> 4, h = bh & 15;
  const int u0 = blockIdx.x * 64;
  const int nrows = (Un - u0 < 64) ? (Un - u0) : 64;
  if (t < 64) {
    int qi = topi[(size_t)bh * Un + ((t < nrows) ? (u0 + t) : 0)];
    qxL[t] = qi;
    rmL[t] = row_max[(size_t)bh * Ln + qi];
  }
  __syncthreads();
#pragma unroll
  for (int c = 0; c < 2; ++c) {
    int f = (c * 256 + t) * 8; int row = f >> 6, col = f & 63;
    size_t go = ((size_t)b * Ln + qxL[row]) * Dn + h * DHn + col;
    *(uint4*)&sQP[row * 80 + col] = *(const uint4*)&Qh[go];
  }
  __syncthreads();
  f16x8 aq[4][2];
#pragma unroll
  for (int mi = 0; mi < 4; ++mi)
#pragma unroll
    for (int ks = 0; ks < 2; ++ks)
      aq[mi][ks] = *(const f16x8*)&sQP[(mi * 16 + lm) * 80 + ks * 32 + q * 8];
  f32x4 oacc[4] = {};
  float dacc[4][4] = {};

  const f16* kbase = Kh + (size_t)b * Ln * Dn + h * DHn;
  const f16* vbase = Vth + (size_t)bh * DHn * Ln;
  for (int kt = 0; kt < 16; ++kt) {
    const int l0 = half * 1024 + kt * 64;
    __syncthreads();
#pragma unroll
    for (int c = 0; c < 2; ++c) {
      int f = (c * 256 + t) * 8; int row = f >> 6, col = f & 63;
      gl_lds16(kbase + (size_t)(l0 + row) * Dn + col, &sK[f]);
      gl_lds16(vbase + (size_t)row * Ln + l0 + col, &sV[f]);
    }
    __syncthreads();
    f16x8 kb[2];
#pragma unroll
    for (int ks = 0; ks < 2; ++ks)
      kb[ks] = *(const f16x8*)&sK[(w * 16 + lm) * 64 + ks * 32 + q * 8];
#pragma unroll
    for (int mi = 0; mi < 4; ++mi) {
      f32x4 acc = {0.f, 0.f, 0.f, 0.f};
      acc = MFMA(aq[mi][0], kb[0], acc);
      acc = MFMA(aq[mi][1], kb[1], acc);
#pragma unroll
      for (int r = 0; r < 4; ++r) {
        int row = mi * 16 + q * 4 + r;
        float p = __expf(acc[r] * PSC - rmL[row]);
        dacc[mi][r] += p;
        sQP[row * 80 + w * 16 + lm] = (f16)(p * SPf);
      }
    }
    __syncthreads();
    f16x8 vb[2];
#pragma unroll
    for (int ks = 0; ks < 2; ++ks)
      vb[ks] = *(const f16x8*)&sV[(w * 16 + lm) * 64 + ks * 32 + q * 8];
#pragma unroll
    for (int mi = 0; mi < 4; ++mi) {
#pragma unroll
      for (int ks = 0; ks < 2; ++ks) {
        f16x8 pf = *(const f16x8*)&sQP[(mi * 16 + lm) * 80 + ks * 32 + q * 8];
        oacc[mi] = MFMA(pf, vb[ks], oacc[mi]);
      }
    }
  }
#pragma unroll
  for (int mi = 0; mi < 4; ++mi)
#pragma unroll
    for (int r = 0; r < 4; ++r) {
      float v = dacc[mi][r];
      v += __shfl_xor(v, 1); v += __shfl_xor(v, 2);
      v += __shfl_xor(v, 4); v += __shfl_xor(v, 8);
      if (lm == 0) dred[mi * 16 + q * 4 + r][w] = v;
    }
  __syncthreads();
  const size_t pbase = ((size_t)half * BHn + bh) * 1280 + u0;
  if (t < 64)
    pD[pbase + t] = dred[t][0] + dred[t][1] + dred[t][2] + dred[t][3];
#pragma unroll
  for (int mi = 0; mi < 4; ++mi)
#pragma unroll
    for (int r = 0; r < 4; ++r) {
      int row = mi * 16 + q * 4 + r;
      pO[(pbase + row) * 64 + w * 16 + lm] = oacc[mi][r];
    }
}

// ---------------- combine halves, normalize, scatter to AOh ----------------
__global__ __launch_bounds__(256) void attn_combine(
    const float* __restrict__ pO, const float* __restrict__ pD,
    const int* __restrict__ topi, f16* __restrict__ AOh) {
  const int t = threadIdx.x;
  const int u0 = blockIdx.x * 64, bh = blockIdx.y, b = bh >> 4, h = bh & 15;
  const int nrows = (Un - u0 < 64) ? (Un - u0) : 64;
  const int row = t >> 2, pg = t & 3;
  if (row >= nrows) return;
  int qi = topi[(size_t)bh * Un + u0 + row];
  size_t i0 = (size_t)bh * 1280 + u0 + row;
  size_t i1 = (size_t)BHn * 1280 + i0;
  float dinv = 1.0f / (pD[i0] + pD[i1]);
  const float* p0 = &pO[i0 * 64 + pg * 16];
  const float* p1 = &pO[i1 * 64 + pg * 16];
  f16 buf[16];
#pragma unroll
  for (int c = 0; c < 4; ++c) {
    float4 a = *(const float4*)&p0[c * 4];
    float4 bb = *(const float4*)&p1[c * 4];
    buf[c * 4 + 0] = (f16)((a.x + bb.x) * dinv);
    buf[c * 4 + 1] = (f16)((a.y + bb.y) * dinv);
    buf[c * 4 + 2] = (f16)((a.z + bb.z) * dinv);
    buf[c * 4 + 3] = (f16)((a.w + bb.w) * dinv);
  }
  f16* dst = &AOh[((size_t)b * Ln + qi) * Dn + h * DHn + pg * 16];
  *(uint4*)&dst[0] = *(uint4*)&buf[0];
  *(uint4*)&dst[8] = *(uint4*)&buf[8];
}

extern "C" void kernel_launch(void* const* d_in, const int* in_sizes, int n_in,
                              void* d_out, int out_size, void* d_ws, size_t ws_size,
                              hipStream_t stream) {
  (void)in_sizes; (void)n_in; (void)out_size; (void)ws_size;
  const float* x  = (const float*)d_in[0];
  const float* Wq = (const float*)d_in[1];
  const float* bq = (const float*)d_in[2];
  const float* Wk = (const float*)d_in[3];
  const float* bk = (const float*)d_in[4];
  const float* Wv = (const float*)d_in[5];
  const float* bv = (const float*)d_in[6];
  const float* Wo = (const float*)d_in[7];
  const float* bo = (const float*)d_in[8];
  float* out = (float*)d_out;

  uint8_t* p = (uint8_t*)d_ws;
  const size_t NE = (size_t)Bn * Ln * Dn;          // 4 Mi elements
  f16* xh = (f16*)p;  p += NE * 2;
  f16* xl = (f16*)p;  p += NE * 2;
  f16* Wt_h = (f16*)p; p += (size_t)4096 * Dn * 2;   // rows 0-3071: QKV cat; 3072-4095: Wo
  f16* Wt_l = (f16*)p; p += (size_t)4096 * Dn * 2;   // only rows 1024-2047 (Wk) populated
  f16* Qbh = (f16*)p; p += NE * 2;
  f16* Kbh = (f16*)p; p += NE * 2;
  float* Kf = (float*)p;  p += NE * 4;
  f16* Vh16 = (f16*)p; p += NE * 2;
  f16* Vth  = (f16*)p; p += NE * 2;
  float* rowmax = (float*)p; p += (size_t)BHn * Ln * 4;
  float* spars  = (float*)p; p += (size_t)BHn * Ln * 4;
  float* ksum   = (float*)p; p += (size_t)BHn * DHn * 4;
  int* topi     = (int*)p;   p += (size_t)BHn * Un * 4;
  int* wrow     = (int*)p;   p += (size_t)BHn * WIN * 4;
  float* spx    = (float*)p; p += (size_t)BHn * WIN * 4;
  float* qx     = (float*)p; p += (size_t)BHn * WIN * 64 * 4;
  float* pD     = (float*)p; p += (size_t)2 * BHn * 1280 * 4;
  float* pO     = (float*)p; p += (size_t)2 * BHn * 1280 * 64 * 4;
  f16* AOh = xh;   // alias: x split dead after projections

  dim3 blk(256);
  hipLaunchKernelGGL(split_kernel, dim3((int)(NE / 4 / 256)), blk, 0, stream, x, xh, xl, (int)(NE / 4));
  hipLaunchKernelGGL(tsplit_w4, dim3(16, 16, 4), blk, 0, stream, Wq, Wk, Wv, Wo, Wt_h, Wt_l);
  hipLaunchKernelGGL(gemm_qv, dim3(16, 32), blk, 0, stream, xh, Wt_h, bq, bv, Qbh, Vh16, Dn);
  hipLaunchKernelGGL(gemm_k, dim3(8, 32), blk, 0, stream, xh, xl, Wt_h, Wt_l, bk, Kf, Kbh, Dn);
  hipLaunchKernelGGL(tsplit_v, dim3(Ln / 64, BHn), blk, 0, stream, Vh16, Vth);
  hipMemsetAsync(ksum, 0, (size_t)BHn * DHn * 4, stream);
  hipLaunchKernelGGL(ksum_part, dim3(8, BHn), blk, 0, stream, Kf, ksum);
  hipLaunchKernelGGL(attn_stats_mfma, dim3(Ln / 128, BHn), blk, 0, stream,
                     Qbh, Kbh, ksum, rowmax, spars);
  hipLaunchKernelGGL(topk_sort, dim3(BHn), dim3(1024), 0, stream, spars, topi, wrow);
  hipLaunchKernelGGL(window_q, dim3(WIN / 16, BHn), blk, 0, stream, x, Wq, bq, wrow, qx);
  hipLaunchKernelGGL(refine_rows, dim3(WIN / 4, BHn), blk, 0, stream, qx, Kf, spx);
  hipLaunchKernelGGL(topk_final, dim3(BHn), dim3(WIN), 0, stream, spx, wrow, topi);
  hipMemsetAsync(AOh, 0, NE * 2, stream);
  hipLaunchKernelGGL(attn_sel_part, dim3((Un + 63) / 64, 2 * BHn), blk, 0, stream,
                     Qbh, Kbh, Vth, topi, rowmax, pO, pD);
  hipLaunchKernelGGL(attn_combine, dim3((Un + 63) / 64, BHn), blk, 0, stream,
                     pO, pD, topi, AOh);
  hipLaunchKernelGGL(gemm_a1, dim3(16, 32), blk, 0, stream, AOh,
                     Wt_h + (size_t)3072 * Dn, bo, ESC_OUT, out, Bn * Ln, Dn, Dn);
}